// Round 5
// baseline (617.611 us; speedup 1.0000x reference)
//
#include <hip/hip_runtime.h>
#include <math.h>

#define NN 50000
#define NE 800000
#define TE (NE + NN)
#define HC 128
#define NEG_SLOPE 0.2f
#define EPSV 1e-5f
#define STATS_BLOCKS 256

// ---------------- CSR build ----------------

__global__ __launch_bounds__(256) void count_k(const int* __restrict__ dst, int* __restrict__ cnt) {
    int e = blockIdx.x * 256 + threadIdx.x;
    if (e >= TE) return;
    int d = (e < NE) ? dst[e] : (e - NE);
    atomicAdd(&cnt[d], 1);
}

__global__ __launch_bounds__(1024) void scan1_k(const int* __restrict__ cnt,
                                                int* __restrict__ excl,
                                                int* __restrict__ aux) {
    __shared__ int wsum[16];
    int tid = threadIdx.x;
    int gid = blockIdx.x * 1024 + tid;
    int lane = tid & 63, wid = tid >> 6;
    int v = (gid < NN) ? cnt[gid] : 0;
    int x = v;
#pragma unroll
    for (int off = 1; off < 64; off <<= 1) {
        int t = __shfl_up(x, off, 64);
        if (lane >= off) x += t;
    }
    if (lane == 63) wsum[wid] = x;
    __syncthreads();
    if (wid == 0 && lane < 16) {
        int y = wsum[lane];
#pragma unroll
        for (int off = 1; off < 16; off <<= 1) {
            int t = __shfl_up(y, off, 64);
            if (lane >= off) y += t;
        }
        wsum[lane] = y;
    }
    __syncthreads();
    int base = (wid > 0) ? wsum[wid - 1] : 0;
    int incl = base + x;
    if (gid < NN) excl[gid] = incl - v;
    if (tid == 1023) aux[blockIdx.x] = incl;
}

__global__ __launch_bounds__(1024) void scan3_k(int* __restrict__ row_ptr,
                                                const int* __restrict__ aux,
                                                int* __restrict__ fill,
                                                int nblk) {
    __shared__ int base_s;
    if (threadIdx.x < 64) {
        int lane = threadIdx.x;
        int v = (lane < nblk) ? aux[lane] : 0;
        int x = v;
#pragma unroll
        for (int off = 1; off < 64; off <<= 1) {
            int t = __shfl_up(x, off, 64);
            if (lane >= off) x += t;
        }
        if (lane == (int)blockIdx.x) base_s = x - v;
    }
    __syncthreads();
    int gid = blockIdx.x * 1024 + threadIdx.x;
    if (gid < NN) {
        int r = row_ptr[gid] + base_s;
        row_ptr[gid] = r;
        fill[gid] = r;
    }
    if (gid == 0) row_ptr[NN] = TE;
}

__global__ __launch_bounds__(256) void scatter_k(const int* __restrict__ srcp,
                                                 const int* __restrict__ dstp,
                                                 int* __restrict__ fill,
                                                 int* __restrict__ col) {
    int e = blockIdx.x * 256 + threadIdx.x;
    if (e >= TE) return;
    int s, d;
    if (e < NE) { s = srcp[e]; d = dstp[e]; } else { s = e - NE; d = s; }
    int pos = atomicAdd(&fill[d], 1);
    col[pos] = s << 9;
}

// ---------------- Dual GEMM (layer 1, raw x input, K=3) ----------------

__global__ __launch_bounds__(256) void gemm_dual(const float* __restrict__ x,
                                                 const float* __restrict__ Wl,
                                                 const float* __restrict__ Wr,
                                                 float* __restrict__ xl,
                                                 float* __restrict__ xr,
                                                 int n, int K) {
    __shared__ float xs[32][72];
    __shared__ float ws[32][260];
    int tid = threadIdx.x;
    int row0 = blockIdx.x * 64;
    int row_t = (tid >> 5) * 8;
    int c0 = (tid & 31) * 4;

    float acc0[8][4];
    float acc1[8][4];
#pragma unroll
    for (int i = 0; i < 8; ++i)
#pragma unroll
        for (int j = 0; j < 4; ++j) { acc0[i][j] = 0.f; acc1[i][j] = 0.f; }

    for (int k0 = 0; k0 < K; k0 += 32) {
        int kc = min(32, K - k0);
        for (int i = tid; i < 64 * kc; i += 256) {
            int r = i / kc;
            int k = i - r * kc;
            int row = row0 + r;
            xs[k][r] = (row < n) ? x[(size_t)row * K + k0 + k] : 0.f;
        }
        for (int i = tid; i < kc * 64; i += 256) {
            int k = i >> 6;
            int cq = i & 63;
            const float* srcp = (cq < 32) ? &Wl[(size_t)(k0 + k) * 128 + cq * 4]
                                          : &Wr[(size_t)(k0 + k) * 128 + (cq - 32) * 4];
            float4 v = *(const float4*)srcp;
            *(float4*)&ws[k][cq * 4] = v;
        }
        __syncthreads();
        for (int k = 0; k < kc; ++k) {
            float4 a0 = *(float4*)&xs[k][row_t];
            float4 a1 = *(float4*)&xs[k][row_t + 4];
            float4 b0 = *(float4*)&ws[k][c0];
            float4 b1 = *(float4*)&ws[k][c0 + 128];
            float av[8] = {a0.x, a0.y, a0.z, a0.w, a1.x, a1.y, a1.z, a1.w};
            float bl[4] = {b0.x, b0.y, b0.z, b0.w};
            float br[4] = {b1.x, b1.y, b1.z, b1.w};
#pragma unroll
            for (int i = 0; i < 8; ++i)
#pragma unroll
                for (int j = 0; j < 4; ++j) {
                    acc0[i][j] += av[i] * bl[j];
                    acc1[i][j] += av[i] * br[j];
                }
        }
        __syncthreads();
    }
#pragma unroll
    for (int i = 0; i < 8; ++i) {
        int row = row0 + row_t + i;
        if (row < n) {
            float4 o0; o0.x = acc0[i][0]; o0.y = acc0[i][1]; o0.z = acc0[i][2]; o0.w = acc0[i][3];
            float4 o1; o1.x = acc1[i][0]; o1.y = acc1[i][1]; o1.z = acc1[i][2]; o1.w = acc1[i][3];
            *(float4*)&xl[(size_t)row * HC + c0] = o0;
            *(float4*)&xr[(size_t)row * HC + c0] = o1;
        }
    }
}

// ---------------- Dual GEMM with fused graph-norm + ReLU (K=64) ----------------
// xs staged once for full K via float4 loads; xs[64][76] -> 2-way banks (free).

__global__ __launch_bounds__(256) void gemm_fused(const float* __restrict__ h,
                                                  const float* __restrict__ cf,
                                                  const float* __restrict__ Wl,
                                                  const float* __restrict__ Wr,
                                                  float* __restrict__ xl,
                                                  float* __restrict__ xr,
                                                  int n) {
    __shared__ float xs[64][76];
    __shared__ float ws[32][260];
    int tid = threadIdx.x;
    int row0 = blockIdx.x * 64;
    int row_t = (tid >> 5) * 8;
    int c0 = (tid & 31) * 4;

    // stage xs (full K=64): thread t loads row r = t>>2, float4s (t&3)+4i
    {
        int r = tid >> 2;
        int b = tid & 3;
        int row = row0 + r;
#pragma unroll
        for (int i = 0; i < 4; ++i) {
            int c = 4 * b + 16 * i;
            float4 v;
            if (row < n) v = *(const float4*)&h[(size_t)row * 64 + c];
            else { v.x = v.y = v.z = v.w = 0.f; }
            float4 cw = *(const float4*)&cf[c];
            float4 cb = *(const float4*)&cf[64 + c];
            xs[c + 0][r] = fmaxf(fmaf(cw.x, v.x, cb.x), 0.f);
            xs[c + 1][r] = fmaxf(fmaf(cw.y, v.y, cb.y), 0.f);
            xs[c + 2][r] = fmaxf(fmaf(cw.z, v.z, cb.z), 0.f);
            xs[c + 3][r] = fmaxf(fmaf(cw.w, v.w, cb.w), 0.f);
        }
    }

    float acc0[8][4];
    float acc1[8][4];
#pragma unroll
    for (int i = 0; i < 8; ++i)
#pragma unroll
        for (int j = 0; j < 4; ++j) { acc0[i][j] = 0.f; acc1[i][j] = 0.f; }

    for (int k0 = 0; k0 < 64; k0 += 32) {
        if (k0) __syncthreads();
        for (int i = tid; i < 32 * 64; i += 256) {
            int k = i >> 6;
            int cq = i & 63;
            const float* srcp = (cq < 32) ? &Wl[(size_t)(k0 + k) * 128 + cq * 4]
                                          : &Wr[(size_t)(k0 + k) * 128 + (cq - 32) * 4];
            float4 v = *(const float4*)srcp;
            *(float4*)&ws[k][cq * 4] = v;
        }
        __syncthreads();
        for (int k = 0; k < 32; ++k) {
            float4 a0 = *(float4*)&xs[k0 + k][row_t];
            float4 a1 = *(float4*)&xs[k0 + k][row_t + 4];
            float4 b0 = *(float4*)&ws[k][c0];
            float4 b1 = *(float4*)&ws[k][c0 + 128];
            float av[8] = {a0.x, a0.y, a0.z, a0.w, a1.x, a1.y, a1.z, a1.w};
            float bl[4] = {b0.x, b0.y, b0.z, b0.w};
            float br[4] = {b1.x, b1.y, b1.z, b1.w};
#pragma unroll
            for (int i = 0; i < 8; ++i)
#pragma unroll
                for (int j = 0; j < 4; ++j) {
                    acc0[i][j] += av[i] * bl[j];
                    acc1[i][j] += av[i] * br[j];
                }
        }
    }
#pragma unroll
    for (int i = 0; i < 8; ++i) {
        int row = row0 + row_t + i;
        if (row < n) {
            float4 o0; o0.x = acc0[i][0]; o0.y = acc0[i][1]; o0.z = acc0[i][2]; o0.w = acc0[i][3];
            float4 o1; o1.x = acc1[i][0]; o1.y = acc1[i][1]; o1.z = acc1[i][2]; o1.w = acc1[i][3];
            *(float4*)&xl[(size_t)row * HC + c0] = o0;
            *(float4*)&xr[(size_t)row * HC + c0] = o1;
        }
    }
}

// ---------------- Attention ----------------
// One wave per dst node. Lanes 0-31: head0 (2 dims/lane), lanes 32-63: head1.
// Software-pipelined 8-edge batches; packed butterfly (16 shuffles, 1 exp per batch);
// masked final batch (no scalar tail).

__global__ __launch_bounds__(256) void attn_k(const float* __restrict__ xl,
                                              const float* __restrict__ xr,
                                              const float* __restrict__ att,
                                              const float* __restrict__ bias,
                                              const int* __restrict__ row_ptr,
                                              const int* __restrict__ coloff,
                                              float* __restrict__ hout) {
    int lane = threadIdx.x & 63;
    int node = blockIdx.x * 4 + (threadIdx.x >> 6);
    if (node >= NN) return;
    int laneh = lane & 31;
    int lanebase = ((lane >> 5) << 8) | (laneh << 2);
    bool b16 = (lane & 16) == 0;
    bool b8 = (lane & 8) == 0;
    bool b4 = (lane & 4) == 0;
    int hb = lane & 32;

    const char* xlc = (const char*)xl;
    const char* xrc = (const char*)xr;
    unsigned nodeoff = (unsigned)node << 9;

    float xrv1 = *(const float*)(xrc + nodeoff + lanebase);
    float xrv2 = *(const float*)(xrc + nodeoff + lanebase + 128);
    float a1 = att[lanebase >> 2];
    float a2 = att[(lanebase >> 2) + 32];
    float c11 = 0.6f * a1, c21 = 0.4f * a1;
    float c12 = 0.6f * a2, c22 = 0.4f * a2;

    float z = 0.f, o1 = 0.f, o2 = 0.f;

    int beg = row_ptr[node];
    int end = row_ptr[node + 1];
    int end1 = end - 1;
    int nb = (end - beg + 7) >> 3;

    float la1[8], la2[8], lb1[8], lb2[8];
    // prologue: gather batch 0 (clamped offsets)
#pragma unroll
    for (int j = 0; j < 8; ++j) {
        int o = coloff[min(beg + j, end1)];
        const char* p = xlc + (unsigned)o + lanebase;
        la1[j] = *(const float*)p;
        la2[j] = *(const float*)(p + 128);
    }

    int idx = beg;
    for (int b = 0; b < nb; ++b) {
        bool more = (b + 1 < nb);
        if (more) {
#pragma unroll
            for (int j = 0; j < 8; ++j) {
                int o = coloff[min(idx + 8 + j, end1)];
                const char* p = xlc + (unsigned)o + lanebase;
                lb1[j] = *(const float*)p;
                lb2[j] = *(const float*)(p + 128);
            }
        }
        // per-edge logit partials (2 dims/lane)
        float u[8];
#pragma unroll
        for (int j = 0; j < 8; ++j) {
            float t1 = la1[j] + xrv1;
            float t2 = la2[j] + xrv2;
            float v = fmaf(c11, t1, c21 * fabsf(t1));
            v = fmaf(c12, t2, v);
            u[j] = fmaf(c22, fabsf(t2), v);
        }
        // packed butterfly: 8 -> 4 -> 2 -> 1 regs across levels 16,8,4,2,1
#pragma unroll
        for (int j = 0; j < 8; ++j) u[j] += __shfl_xor(u[j], 16, 64);
        float w0 = b16 ? u[0] : u[1];
        float w1 = b16 ? u[2] : u[3];
        float w2 = b16 ? u[4] : u[5];
        float w3 = b16 ? u[6] : u[7];
        w0 += __shfl_xor(w0, 8, 64);
        w1 += __shfl_xor(w1, 8, 64);
        w2 += __shfl_xor(w2, 8, 64);
        w3 += __shfl_xor(w3, 8, 64);
        float v0 = b8 ? w0 : w1;
        float v1 = b8 ? w2 : w3;
        v0 += __shfl_xor(v0, 4, 64);
        v1 += __shfl_xor(v1, 4, 64);
        float t = b4 ? v0 : v1;
        t += __shfl_xor(t, 2, 64);
        t += __shfl_xor(t, 1, 64);
        float P = __expf(t);
        // broadcast per-edge weights (head-local lanes)
        float p0 = __shfl(P, hb + 0, 64);
        float p1 = __shfl(P, hb + 16, 64);
        float p2 = __shfl(P, hb + 8, 64);
        float p3 = __shfl(P, hb + 24, 64);
        float p4 = __shfl(P, hb + 4, 64);
        float p5 = __shfl(P, hb + 20, 64);
        float p6 = __shfl(P, hb + 12, 64);
        float p7 = __shfl(P, hb + 28, 64);
        int rem = end - idx;  // >8 except on last batch
        if (rem < 8) {
            if (rem < 2) p1 = 0.f;
            if (rem < 3) p2 = 0.f;
            if (rem < 4) p3 = 0.f;
            if (rem < 5) p4 = 0.f;
            if (rem < 6) p5 = 0.f;
            if (rem < 7) p6 = 0.f;
            p7 = 0.f;
        }
        z += ((p0 + p1) + (p2 + p3)) + ((p4 + p5) + (p6 + p7));
        o1 = fmaf(p0, la1[0], o1); o2 = fmaf(p0, la2[0], o2);
        o1 = fmaf(p1, la1[1], o1); o2 = fmaf(p1, la2[1], o2);
        o1 = fmaf(p2, la1[2], o1); o2 = fmaf(p2, la2[2], o2);
        o1 = fmaf(p3, la1[3], o1); o2 = fmaf(p3, la2[3], o2);
        o1 = fmaf(p4, la1[4], o1); o2 = fmaf(p4, la2[4], o2);
        o1 = fmaf(p5, la1[5], o1); o2 = fmaf(p5, la2[5], o2);
        o1 = fmaf(p6, la1[6], o1); o2 = fmaf(p6, la2[6], o2);
        o1 = fmaf(p7, la1[7], o1); o2 = fmaf(p7, la2[7], o2);
        if (more) {
#pragma unroll
            for (int j = 0; j < 8; ++j) { la1[j] = lb1[j]; la2[j] = lb2[j]; }
        }
        idx += 8;
    }
    float zi = 1.0f / z;
    float t1 = o1 * zi;
    float t2 = o2 * zi;
    float u1 = __shfl_xor(t1, 32, 64);
    float u2 = __shfl_xor(t2, 32, 64);
    if (lane < 32) {
        float r1 = fmaf(0.5f, t1 + u1, bias[laneh]);
        float r2 = fmaf(0.5f, t2 + u2, bias[laneh + 32]);
        float* q = hout + (size_t)node * 64 + laneh;
        q[0] = r1;
        q[32] = r2;
    }
}

// ---------------- GraphNorm stats + coefficient (fused via last-block ticket) ----------------

__global__ __launch_bounds__(256) void colstats_k(const float* __restrict__ h,
                                                  const float* __restrict__ gw,
                                                  const float* __restrict__ gb,
                                                  const float* __restrict__ gm,
                                                  float* __restrict__ stats,
                                                  int* __restrict__ ticket,
                                                  float* __restrict__ cf) {
    int c = threadIdx.x & 63;
    int rg = threadIdx.x >> 6;
    float s = 0.f, s2 = 0.f;
    for (int r = blockIdx.x * 4 + rg; r < NN; r += gridDim.x * 4) {
        float v = h[(size_t)r * 64 + c];
        s += v;
        s2 += v * v;
    }
    __shared__ float b1[4][64];
    __shared__ float b2[4][64];
    b1[rg][c] = s;
    b2[rg][c] = s2;
    __syncthreads();
    if (threadIdx.x < 64) {
        s = b1[0][c] + b1[1][c] + b1[2][c] + b1[3][c];
        s2 = b2[0][c] + b2[1][c] + b2[2][c] + b2[3][c];
        atomicAdd(&stats[c], s);
        atomicAdd(&stats[64 + c], s2);
    }
    __shared__ int lastFlag;
    __threadfence();
    if (threadIdx.x == 0) {
        int t = __hip_atomic_fetch_add(ticket, 1, __ATOMIC_ACQ_REL, __HIP_MEMORY_SCOPE_AGENT);
        lastFlag = (t == (int)gridDim.x - 1);
    }
    __syncthreads();
    if (lastFlag && threadIdx.x < 64) {
        float sum = __hip_atomic_load(&stats[c], __ATOMIC_RELAXED, __HIP_MEMORY_SCOPE_AGENT);
        float sum2 = __hip_atomic_load(&stats[64 + c], __ATOMIC_RELAXED, __HIP_MEMORY_SCOPE_AGENT);
        float inv_n = 1.f / (float)NN;
        float mu = sum * inv_n;
        float ex2 = sum2 * inv_n;
        float g = gm[c];
        float var = ex2 - 2.f * g * mu * mu + g * g * mu * mu;
        float rs = rsqrtf(var + EPSV);
        cf[c] = gw[c] * rs;
        cf[64 + c] = gb[c] - gw[c] * rs * g * mu;
    }
}

__global__ __launch_bounds__(256) void apply_k(const float* __restrict__ h,
                                               const float* __restrict__ cf,
                                               float* __restrict__ y) {
    int i = blockIdx.x * 256 + threadIdx.x;
    if (i >= NN * 64) return;
    int c = i & 63;
    float v = fmaf(cf[c], h[i], cf[64 + c]);
    y[i] = fmaxf(v, 0.f);
}

// ---------------- launch ----------------

extern "C" void kernel_launch(void* const* d_in, const int* in_sizes, int n_in,
                              void* d_out, int out_size, void* d_ws, size_t ws_size,
                              hipStream_t stream) {
    const float* x0 = (const float*)d_in[0];
    const int* ei = (const int*)d_in[1];
    const int* srcp = ei;
    const int* dstp = ei + NE;

    const float* Wl[3], *Wr[3], *att[3], *bv[3], *gw[3], *gb[3], *gm[3];
    for (int l = 0; l < 3; ++l) {
        int base = 2 + 7 * l;
        Wl[l] = (const float*)d_in[base + 0];
        Wr[l] = (const float*)d_in[base + 1];
        att[l] = (const float*)d_in[base + 2];
        bv[l] = (const float*)d_in[base + 3];
        gw[l] = (const float*)d_in[base + 4];
        gb[l] = (const float*)d_in[base + 5];
        gm[l] = (const float*)d_in[base + 6];
    }

    char* p = (char*)d_ws;
    auto take = [&](size_t bytes) -> void* {
        void* r = (void*)p;
        p += (bytes + 255) & ~(size_t)255;
        return r;
    };
    float* xl = (float*)take((size_t)NN * 128 * 4);
    float* xr = (float*)take((size_t)NN * 128 * 4);
    float* hb = (float*)take((size_t)NN * 64 * 4);
    size_t zero_bytes = 3 * 128 * 4 + 3 * 4 + (size_t)NN * 4;
    char* zr = (char*)take(zero_bytes);
    float* stats = (float*)zr;
    int* tickets = (int*)(zr + 3 * 128 * 4);
    int* cnt = (int*)(zr + 3 * 128 * 4 + 3 * 4);
    int* row_ptr = (int*)take((size_t)(NN + 1) * 4);
    int* fill = (int*)take((size_t)NN * 4);
    int* col = (int*)take((size_t)TE * 4);
    int* aux = (int*)take(64 * 4);
    float* cfb = (float*)take(3 * 128 * 4);

    hipMemsetAsync(zr, 0, zero_bytes, stream);

    int nblk = (NN + 1023) / 1024;
    int egrid = (TE + 255) / 256;
    count_k<<<egrid, 256, 0, stream>>>(dstp, cnt);
    scan1_k<<<nblk, 1024, 0, stream>>>(cnt, row_ptr, aux);
    scan3_k<<<nblk, 1024, 0, stream>>>(row_ptr, aux, fill, nblk);
    scatter_k<<<egrid, 256, 0, stream>>>(srcp, dstp, fill, col);

    int ggrid = (NN + 63) / 64;
    int agrid = (NN + 3) / 4;
    for (int l = 0; l < 3; ++l) {
        float* cf = cfb + l * 128;
        if (l == 0)
            gemm_dual<<<ggrid, 256, 0, stream>>>(x0, Wl[0], Wr[0], xl, xr, NN, 3);
        else
            gemm_fused<<<ggrid, 256, 0, stream>>>(hb, cfb + (l - 1) * 128, Wl[l], Wr[l], xl, xr, NN);
        attn_k<<<agrid, 256, 0, stream>>>(xl, xr, att[l], bv[l], row_ptr, col, hb);
        colstats_k<<<STATS_BLOCKS, 256, 0, stream>>>(hb, gw[l], gb[l], gm[l],
                                                     stats + l * 128, tickets + l, cf);
    }
    apply_k<<<(NN * 64 + 255) / 256, 256, 0, stream>>>(hb, cfb + 2 * 128, (float*)d_out);
}

// Round 6
// 524.494 us; speedup vs baseline: 1.1775x; 1.1775x over previous
//
#include <hip/hip_runtime.h>
#include <math.h>

#define NN 50000
#define NE 800000
#define TE (NE + NN)
#define HC 128
#define NEG_SLOPE 0.2f
#define EPSV 1e-5f
#define STATS_BLOCKS 256

// ---------------- CSR build ----------------
// count_k's atomic return value IS the edge's within-dst rank -> scatter needs no atomics.

__global__ __launch_bounds__(256) void count_k(const int* __restrict__ dst,
                                               int* __restrict__ cnt,
                                               int* __restrict__ rank) {
    int e = blockIdx.x * 256 + threadIdx.x;
    if (e >= TE) return;
    int d = (e < NE) ? dst[e] : (e - NE);
    rank[e] = atomicAdd(&cnt[d], 1);
}

__global__ __launch_bounds__(1024) void scan1_k(const int* __restrict__ cnt,
                                                int* __restrict__ excl,
                                                int* __restrict__ aux) {
    __shared__ int wsum[16];
    int tid = threadIdx.x;
    int gid = blockIdx.x * 1024 + tid;
    int lane = tid & 63, wid = tid >> 6;
    int v = (gid < NN) ? cnt[gid] : 0;
    int x = v;
#pragma unroll
    for (int off = 1; off < 64; off <<= 1) {
        int t = __shfl_up(x, off, 64);
        if (lane >= off) x += t;
    }
    if (lane == 63) wsum[wid] = x;
    __syncthreads();
    if (wid == 0 && lane < 16) {
        int y = wsum[lane];
#pragma unroll
        for (int off = 1; off < 16; off <<= 1) {
            int t = __shfl_up(y, off, 64);
            if (lane >= off) y += t;
        }
        wsum[lane] = y;
    }
    __syncthreads();
    int base = (wid > 0) ? wsum[wid - 1] : 0;
    int incl = base + x;
    if (gid < NN) excl[gid] = incl - v;
    if (tid == 1023) aux[blockIdx.x] = incl;
}

__global__ __launch_bounds__(1024) void scan3_k(int* __restrict__ row_ptr,
                                                const int* __restrict__ aux,
                                                int nblk) {
    __shared__ int base_s;
    if (threadIdx.x < 64) {
        int lane = threadIdx.x;
        int v = (lane < nblk) ? aux[lane] : 0;
        int x = v;
#pragma unroll
        for (int off = 1; off < 64; off <<= 1) {
            int t = __shfl_up(x, off, 64);
            if (lane >= off) x += t;
        }
        if (lane == (int)blockIdx.x) base_s = x - v;
    }
    __syncthreads();
    int gid = blockIdx.x * 1024 + threadIdx.x;
    if (gid < NN) row_ptr[gid] = row_ptr[gid] + base_s;
    if (gid == 0) row_ptr[NN] = TE;
}

// col[] stores BYTE offsets (src * 512); no atomics (rank precomputed).
__global__ __launch_bounds__(256) void scatter_k(const int* __restrict__ srcp,
                                                 const int* __restrict__ dstp,
                                                 const int* __restrict__ row_ptr,
                                                 const int* __restrict__ rank,
                                                 int* __restrict__ col) {
    int e = blockIdx.x * 256 + threadIdx.x;
    if (e >= TE) return;
    int s, d;
    if (e < NE) { s = srcp[e]; d = dstp[e]; } else { s = e - NE; d = s; }
    col[row_ptr[d] + rank[e]] = s << 9;
}

// ---------------- Dual GEMM (layer 1, raw x input, K=3) ----------------

__global__ __launch_bounds__(256) void gemm_dual(const float* __restrict__ x,
                                                 const float* __restrict__ Wl,
                                                 const float* __restrict__ Wr,
                                                 float* __restrict__ xl,
                                                 float* __restrict__ xr,
                                                 int n, int K) {
    __shared__ float xs[32][72];
    __shared__ float ws[32][260];
    int tid = threadIdx.x;
    int row0 = blockIdx.x * 64;
    int row_t = (tid >> 5) * 8;
    int c0 = (tid & 31) * 4;

    float acc0[8][4];
    float acc1[8][4];
#pragma unroll
    for (int i = 0; i < 8; ++i)
#pragma unroll
        for (int j = 0; j < 4; ++j) { acc0[i][j] = 0.f; acc1[i][j] = 0.f; }

    for (int k0 = 0; k0 < K; k0 += 32) {
        int kc = min(32, K - k0);
        for (int i = tid; i < 64 * kc; i += 256) {
            int r = i / kc;
            int k = i - r * kc;
            int row = row0 + r;
            xs[k][r] = (row < n) ? x[(size_t)row * K + k0 + k] : 0.f;
        }
        for (int i = tid; i < kc * 64; i += 256) {
            int k = i >> 6;
            int cq = i & 63;
            const float* srcp = (cq < 32) ? &Wl[(size_t)(k0 + k) * 128 + cq * 4]
                                          : &Wr[(size_t)(k0 + k) * 128 + (cq - 32) * 4];
            float4 v = *(const float4*)srcp;
            *(float4*)&ws[k][cq * 4] = v;
        }
        __syncthreads();
        for (int k = 0; k < kc; ++k) {
            float4 a0 = *(float4*)&xs[k][row_t];
            float4 a1 = *(float4*)&xs[k][row_t + 4];
            float4 b0 = *(float4*)&ws[k][c0];
            float4 b1 = *(float4*)&ws[k][c0 + 128];
            float av[8] = {a0.x, a0.y, a0.z, a0.w, a1.x, a1.y, a1.z, a1.w};
            float bl[4] = {b0.x, b0.y, b0.z, b0.w};
            float br[4] = {b1.x, b1.y, b1.z, b1.w};
#pragma unroll
            for (int i = 0; i < 8; ++i)
#pragma unroll
                for (int j = 0; j < 4; ++j) {
                    acc0[i][j] += av[i] * bl[j];
                    acc1[i][j] += av[i] * br[j];
                }
        }
        __syncthreads();
    }
#pragma unroll
    for (int i = 0; i < 8; ++i) {
        int row = row0 + row_t + i;
        if (row < n) {
            float4 o0; o0.x = acc0[i][0]; o0.y = acc0[i][1]; o0.z = acc0[i][2]; o0.w = acc0[i][3];
            float4 o1; o1.x = acc1[i][0]; o1.y = acc1[i][1]; o1.z = acc1[i][2]; o1.w = acc1[i][3];
            *(float4*)&xl[(size_t)row * HC + c0] = o0;
            *(float4*)&xr[(size_t)row * HC + c0] = o1;
        }
    }
}

// ---------------- Dual GEMM with fused graph-norm + ReLU (K=64) ----------------

__global__ __launch_bounds__(256) void gemm_fused(const float* __restrict__ h,
                                                  const float* __restrict__ cf,
                                                  const float* __restrict__ Wl,
                                                  const float* __restrict__ Wr,
                                                  float* __restrict__ xl,
                                                  float* __restrict__ xr,
                                                  int n) {
    __shared__ float xs[64][76];
    __shared__ float ws[32][260];
    int tid = threadIdx.x;
    int row0 = blockIdx.x * 64;
    int row_t = (tid >> 5) * 8;
    int c0 = (tid & 31) * 4;

    {
        int r = tid >> 2;
        int b = tid & 3;
        int row = row0 + r;
#pragma unroll
        for (int i = 0; i < 4; ++i) {
            int c = 4 * b + 16 * i;
            float4 v;
            if (row < n) v = *(const float4*)&h[(size_t)row * 64 + c];
            else { v.x = v.y = v.z = v.w = 0.f; }
            float4 cw = *(const float4*)&cf[c];
            float4 cb = *(const float4*)&cf[64 + c];
            xs[c + 0][r] = fmaxf(fmaf(cw.x, v.x, cb.x), 0.f);
            xs[c + 1][r] = fmaxf(fmaf(cw.y, v.y, cb.y), 0.f);
            xs[c + 2][r] = fmaxf(fmaf(cw.z, v.z, cb.z), 0.f);
            xs[c + 3][r] = fmaxf(fmaf(cw.w, v.w, cb.w), 0.f);
        }
    }

    float acc0[8][4];
    float acc1[8][4];
#pragma unroll
    for (int i = 0; i < 8; ++i)
#pragma unroll
        for (int j = 0; j < 4; ++j) { acc0[i][j] = 0.f; acc1[i][j] = 0.f; }

    for (int k0 = 0; k0 < 64; k0 += 32) {
        if (k0) __syncthreads();
        for (int i = tid; i < 32 * 64; i += 256) {
            int k = i >> 6;
            int cq = i & 63;
            const float* srcp = (cq < 32) ? &Wl[(size_t)(k0 + k) * 128 + cq * 4]
                                          : &Wr[(size_t)(k0 + k) * 128 + (cq - 32) * 4];
            float4 v = *(const float4*)srcp;
            *(float4*)&ws[k][cq * 4] = v;
        }
        __syncthreads();
        for (int k = 0; k < 32; ++k) {
            float4 a0 = *(float4*)&xs[k0 + k][row_t];
            float4 a1 = *(float4*)&xs[k0 + k][row_t + 4];
            float4 b0 = *(float4*)&ws[k][c0];
            float4 b1 = *(float4*)&ws[k][c0 + 128];
            float av[8] = {a0.x, a0.y, a0.z, a0.w, a1.x, a1.y, a1.z, a1.w};
            float bl[4] = {b0.x, b0.y, b0.z, b0.w};
            float br[4] = {b1.x, b1.y, b1.z, b1.w};
#pragma unroll
            for (int i = 0; i < 8; ++i)
#pragma unroll
                for (int j = 0; j < 4; ++j) {
                    acc0[i][j] += av[i] * bl[j];
                    acc1[i][j] += av[i] * br[j];
                }
        }
    }
#pragma unroll
    for (int i = 0; i < 8; ++i) {
        int row = row0 + row_t + i;
        if (row < n) {
            float4 o0; o0.x = acc0[i][0]; o0.y = acc0[i][1]; o0.z = acc0[i][2]; o0.w = acc0[i][3];
            float4 o1; o1.x = acc1[i][0]; o1.y = acc1[i][1]; o1.z = acc1[i][2]; o1.w = acc1[i][3];
            *(float4*)&xl[(size_t)row * HC + c0] = o0;
            *(float4*)&xr[(size_t)row * HC + c0] = o1;
        }
    }
}

// ---------------- Attention (R4 structure: 8-gather ILP, no explicit pipeline) ----------------
// One wave per dst node. Lanes 0-31: head0 (2 dims/lane), lanes 32-63: head1.

__global__ __launch_bounds__(256) void attn_k(const float* __restrict__ xl,
                                              const float* __restrict__ xr,
                                              const float* __restrict__ att,
                                              const float* __restrict__ bias,
                                              const int* __restrict__ row_ptr,
                                              const int* __restrict__ coloff,
                                              float* __restrict__ hout) {
    int lane = threadIdx.x & 63;
    int node = blockIdx.x * 4 + (threadIdx.x >> 6);
    if (node >= NN) return;
    int laneh = lane & 31;
    int lanebase = ((lane >> 5) << 8) | (laneh << 2);
    bool b16 = (lane & 16) == 0;

    const char* xlc = (const char*)xl;
    const char* xrc = (const char*)xr;
    unsigned nodeoff = (unsigned)node << 9;

    float xrv1 = *(const float*)(xrc + nodeoff + lanebase);
    float xrv2 = *(const float*)(xrc + nodeoff + lanebase + 128);
    float a1 = att[lanebase >> 2];
    float a2 = att[(lanebase >> 2) + 32];
    float c11 = 0.6f * a1, c21 = 0.4f * a1;
    float c12 = 0.6f * a2, c22 = 0.4f * a2;

    float z = 0.f, o1 = 0.f, o2 = 0.f;

    int beg = row_ptr[node];
    int end = row_ptr[node + 1];
    int idx = beg;
    for (; idx + 8 <= end; idx += 8) {
        int offs[8];
#pragma unroll
        for (int j = 0; j < 8; ++j) offs[j] = coloff[idx + j];
        float l1[8], l2[8], u[8];
#pragma unroll
        for (int j = 0; j < 8; ++j) {
            const char* p = xlc + (unsigned)offs[j] + lanebase;
            l1[j] = *(const float*)p;
            l2[j] = *(const float*)(p + 128);
        }
#pragma unroll
        for (int j = 0; j < 8; ++j) {
            float t1 = l1[j] + xrv1;
            float t2 = l2[j] + xrv2;
            float v = fmaf(c11, t1, c21 * fabsf(t1));
            v = fmaf(c12, t2, v);
            u[j] = fmaf(c22, fabsf(t2), v);
        }
#pragma unroll
        for (int j = 0; j < 8; ++j) u[j] += __shfl_xor(u[j], 16, 64);
        float w0 = b16 ? u[0] : u[1];
        float w1 = b16 ? u[2] : u[3];
        float w2 = b16 ? u[4] : u[5];
        float w3 = b16 ? u[6] : u[7];
#pragma unroll
        for (int off = 8; off > 0; off >>= 1) {
            w0 += __shfl_xor(w0, off, 64);
            w1 += __shfl_xor(w1, off, 64);
            w2 += __shfl_xor(w2, off, 64);
            w3 += __shfl_xor(w3, off, 64);
        }
        float s0 = __shfl_xor(w0, 16, 64);
        float s1 = __shfl_xor(w1, 16, 64);
        float s2 = __shfl_xor(w2, 16, 64);
        float s3 = __shfl_xor(w3, 16, 64);
        float p0 = __expf(b16 ? w0 : s0);
        float p1 = __expf(b16 ? s0 : w0);
        float p2 = __expf(b16 ? w1 : s1);
        float p3 = __expf(b16 ? s1 : w1);
        float p4 = __expf(b16 ? w2 : s2);
        float p5 = __expf(b16 ? s2 : w2);
        float p6 = __expf(b16 ? w3 : s3);
        float p7 = __expf(b16 ? s3 : w3);
        z += ((p0 + p1) + (p2 + p3)) + ((p4 + p5) + (p6 + p7));
        o1 = fmaf(p0, l1[0], o1); o2 = fmaf(p0, l2[0], o2);
        o1 = fmaf(p1, l1[1], o1); o2 = fmaf(p1, l2[1], o2);
        o1 = fmaf(p2, l1[2], o1); o2 = fmaf(p2, l2[2], o2);
        o1 = fmaf(p3, l1[3], o1); o2 = fmaf(p3, l2[3], o2);
        o1 = fmaf(p4, l1[4], o1); o2 = fmaf(p4, l2[4], o2);
        o1 = fmaf(p5, l1[5], o1); o2 = fmaf(p5, l2[5], o2);
        o1 = fmaf(p6, l1[6], o1); o2 = fmaf(p6, l2[6], o2);
        o1 = fmaf(p7, l1[7], o1); o2 = fmaf(p7, l2[7], o2);
    }
    for (; idx < end; ++idx) {
        const char* p = xlc + (unsigned)coloff[idx] + lanebase;
        float l1 = *(const float*)p;
        float l2 = *(const float*)(p + 128);
        float t1 = l1 + xrv1;
        float t2 = l2 + xrv2;
        float v = fmaf(c11, t1, c21 * fabsf(t1));
        v = fmaf(c12, t2, v);
        float u = fmaf(c22, fabsf(t2), v);
#pragma unroll
        for (int off = 16; off > 0; off >>= 1) u += __shfl_xor(u, off, 64);
        float pj = __expf(u);
        z += pj;
        o1 = fmaf(pj, l1, o1);
        o2 = fmaf(pj, l2, o2);
    }
    float zi = 1.0f / z;
    float t1 = o1 * zi;
    float t2 = o2 * zi;
    float u1 = __shfl_xor(t1, 32, 64);
    float u2 = __shfl_xor(t2, 32, 64);
    if (lane < 32) {
        float r1 = fmaf(0.5f, t1 + u1, bias[laneh]);
        float r2 = fmaf(0.5f, t2 + u2, bias[laneh + 32]);
        float* q = hout + (size_t)node * 64 + laneh;
        q[0] = r1;
        q[32] = r2;
    }
}

// ---------------- GraphNorm stats + coefficient (fused via last-block ticket) ----------------

__global__ __launch_bounds__(256) void colstats_k(const float* __restrict__ h,
                                                  const float* __restrict__ gw,
                                                  const float* __restrict__ gb,
                                                  const float* __restrict__ gm,
                                                  float* __restrict__ stats,
                                                  int* __restrict__ ticket,
                                                  float* __restrict__ cf) {
    int c = threadIdx.x & 63;
    int rg = threadIdx.x >> 6;
    float s = 0.f, s2 = 0.f;
    for (int r = blockIdx.x * 4 + rg; r < NN; r += gridDim.x * 4) {
        float v = h[(size_t)r * 64 + c];
        s += v;
        s2 += v * v;
    }
    __shared__ float b1[4][64];
    __shared__ float b2[4][64];
    b1[rg][c] = s;
    b2[rg][c] = s2;
    __syncthreads();
    if (threadIdx.x < 64) {
        s = b1[0][c] + b1[1][c] + b1[2][c] + b1[3][c];
        s2 = b2[0][c] + b2[1][c] + b2[2][c] + b2[3][c];
        atomicAdd(&stats[c], s);
        atomicAdd(&stats[64 + c], s2);
    }
    __shared__ int lastFlag;
    __threadfence();
    if (threadIdx.x == 0) {
        int t = __hip_atomic_fetch_add(ticket, 1, __ATOMIC_ACQ_REL, __HIP_MEMORY_SCOPE_AGENT);
        lastFlag = (t == (int)gridDim.x - 1);
    }
    __syncthreads();
    if (lastFlag && threadIdx.x < 64) {
        float sum = __hip_atomic_load(&stats[c], __ATOMIC_RELAXED, __HIP_MEMORY_SCOPE_AGENT);
        float sum2 = __hip_atomic_load(&stats[64 + c], __ATOMIC_RELAXED, __HIP_MEMORY_SCOPE_AGENT);
        float inv_n = 1.f / (float)NN;
        float mu = sum * inv_n;
        float ex2 = sum2 * inv_n;
        float g = gm[c];
        float var = ex2 - 2.f * g * mu * mu + g * g * mu * mu;
        float rs = rsqrtf(var + EPSV);
        cf[c] = gw[c] * rs;
        cf[64 + c] = gb[c] - gw[c] * rs * g * mu;
    }
}

__global__ __launch_bounds__(256) void apply_k(const float* __restrict__ h,
                                               const float* __restrict__ cf,
                                               float* __restrict__ y) {
    int i = blockIdx.x * 256 + threadIdx.x;
    if (i >= NN * 64) return;
    int c = i & 63;
    float v = fmaf(cf[c], h[i], cf[64 + c]);
    y[i] = fmaxf(v, 0.f);
}

// ---------------- launch ----------------

extern "C" void kernel_launch(void* const* d_in, const int* in_sizes, int n_in,
                              void* d_out, int out_size, void* d_ws, size_t ws_size,
                              hipStream_t stream) {
    const float* x0 = (const float*)d_in[0];
    const int* ei = (const int*)d_in[1];
    const int* srcp = ei;
    const int* dstp = ei + NE;

    const float* Wl[3], *Wr[3], *att[3], *bv[3], *gw[3], *gb[3], *gm[3];
    for (int l = 0; l < 3; ++l) {
        int base = 2 + 7 * l;
        Wl[l] = (const float*)d_in[base + 0];
        Wr[l] = (const float*)d_in[base + 1];
        att[l] = (const float*)d_in[base + 2];
        bv[l] = (const float*)d_in[base + 3];
        gw[l] = (const float*)d_in[base + 4];
        gb[l] = (const float*)d_in[base + 5];
        gm[l] = (const float*)d_in[base + 6];
    }

    char* p = (char*)d_ws;
    auto take = [&](size_t bytes) -> void* {
        void* r = (void*)p;
        p += (bytes + 255) & ~(size_t)255;
        return r;
    };
    float* xl = (float*)take((size_t)NN * 128 * 4);
    float* xr = (float*)take((size_t)NN * 128 * 4);
    float* hb = (float*)take((size_t)NN * 64 * 4);
    size_t zero_bytes = 3 * 128 * 4 + 3 * 4 + (size_t)NN * 4;
    char* zr = (char*)take(zero_bytes);
    float* stats = (float*)zr;
    int* tickets = (int*)(zr + 3 * 128 * 4);
    int* cnt = (int*)(zr + 3 * 128 * 4 + 3 * 4);
    int* row_ptr = (int*)take((size_t)(NN + 1) * 4);
    int* rank = (int*)take((size_t)TE * 4);
    int* col = (int*)take((size_t)TE * 4);
    int* aux = (int*)take(64 * 4);
    float* cfb = (float*)take(3 * 128 * 4);

    hipMemsetAsync(zr, 0, zero_bytes, stream);

    int nblk = (NN + 1023) / 1024;
    int egrid = (TE + 255) / 256;
    count_k<<<egrid, 256, 0, stream>>>(dstp, cnt, rank);
    scan1_k<<<nblk, 1024, 0, stream>>>(cnt, row_ptr, aux);
    scan3_k<<<nblk, 1024, 0, stream>>>(row_ptr, aux, nblk);
    scatter_k<<<egrid, 256, 0, stream>>>(srcp, dstp, row_ptr, rank, col);

    int ggrid = (NN + 63) / 64;
    int agrid = (NN + 3) / 4;
    for (int l = 0; l < 3; ++l) {
        float* cf = cfb + l * 128;
        if (l == 0)
            gemm_dual<<<ggrid, 256, 0, stream>>>(x0, Wl[0], Wr[0], xl, xr, NN, 3);
        else
            gemm_fused<<<ggrid, 256, 0, stream>>>(hb, cfb + (l - 1) * 128, Wl[l], Wr[l], xl, xr, NN);
        attn_k<<<agrid, 256, 0, stream>>>(xl, xr, att[l], bv[l], row_ptr, col, hb);
        colstats_k<<<STATS_BLOCKS, 256, 0, stream>>>(hb, gw[l], gb[l], gm[l],
                                                     stats + l * 128, tickets + l, cf);
    }
    apply_k<<<(NN * 64 + 255) / 256, 256, 0, stream>>>(hb, cfb + 2 * 128, (float*)d_out);
}

// Round 7
// 492.520 us; speedup vs baseline: 1.2540x; 1.0649x over previous
//
#include <hip/hip_runtime.h>
#include <math.h>

#define NN 50000
#define NE 800000
#define TE (NE + NN)
#define HC 128
#define NEG_SLOPE 0.2f
#define EPSV 1e-5f
#define STATS_BLOCKS 256

__device__ __forceinline__ unsigned short f2bf(float x) {
    unsigned u = __float_as_uint(x);
    unsigned r = (u + 0x7fff + ((u >> 16) & 1)) >> 16;  // RNE
    return (unsigned short)r;
}

// ---------------- CSR build ----------------
// count_k's atomic return value IS the edge's within-dst rank -> scatter needs no atomics.

__global__ __launch_bounds__(256) void count_k(const int* __restrict__ dst,
                                               int* __restrict__ cnt,
                                               int* __restrict__ rank) {
    int e = blockIdx.x * 256 + threadIdx.x;
    if (e >= TE) return;
    int d = (e < NE) ? dst[e] : (e - NE);
    rank[e] = atomicAdd(&cnt[d], 1);
}

__global__ __launch_bounds__(1024) void scan1_k(const int* __restrict__ cnt,
                                                int* __restrict__ excl,
                                                int* __restrict__ aux) {
    __shared__ int wsum[16];
    int tid = threadIdx.x;
    int gid = blockIdx.x * 1024 + tid;
    int lane = tid & 63, wid = tid >> 6;
    int v = (gid < NN) ? cnt[gid] : 0;
    int x = v;
#pragma unroll
    for (int off = 1; off < 64; off <<= 1) {
        int t = __shfl_up(x, off, 64);
        if (lane >= off) x += t;
    }
    if (lane == 63) wsum[wid] = x;
    __syncthreads();
    if (wid == 0 && lane < 16) {
        int y = wsum[lane];
#pragma unroll
        for (int off = 1; off < 16; off <<= 1) {
            int t = __shfl_up(y, off, 64);
            if (lane >= off) y += t;
        }
        wsum[lane] = y;
    }
    __syncthreads();
    int base = (wid > 0) ? wsum[wid - 1] : 0;
    int incl = base + x;
    if (gid < NN) excl[gid] = incl - v;
    if (tid == 1023) aux[blockIdx.x] = incl;
}

__global__ __launch_bounds__(1024) void scan3_k(int* __restrict__ row_ptr,
                                                const int* __restrict__ aux,
                                                int nblk) {
    __shared__ int base_s;
    if (threadIdx.x < 64) {
        int lane = threadIdx.x;
        int v = (lane < nblk) ? aux[lane] : 0;
        int x = v;
#pragma unroll
        for (int off = 1; off < 64; off <<= 1) {
            int t = __shfl_up(x, off, 64);
            if (lane >= off) x += t;
        }
        if (lane == (int)blockIdx.x) base_s = x - v;
    }
    __syncthreads();
    int gid = blockIdx.x * 1024 + threadIdx.x;
    if (gid < NN) row_ptr[gid] = row_ptr[gid] + base_s;
    if (gid == 0) row_ptr[NN] = TE;
}

// col[] stores BYTE offsets into the packed bf16 array (src * 256); no atomics.
__global__ __launch_bounds__(256) void scatter_k(const int* __restrict__ srcp,
                                                 const int* __restrict__ dstp,
                                                 const int* __restrict__ row_ptr,
                                                 const int* __restrict__ rank,
                                                 int* __restrict__ col) {
    int e = blockIdx.x * 256 + threadIdx.x;
    if (e >= TE) return;
    int s, d;
    if (e < NE) { s = srcp[e]; d = dstp[e]; } else { s = e - NE; d = s; }
    col[row_ptr[d] + rank[e]] = s << 8;
}

// ---- packed xl epilogue store: acc0 row of 4 cols starting at c0 ----
// xlp row (256 B): head h occupies bytes [h*128, h*128+128); pair (d, d+32)
// packed into the uint at byte h*128 + 4*d  (lo ushort = d, hi ushort = d+32).
__device__ __forceinline__ void store_xlp(char* xlp, int row, int c0, const float* a) {
    unsigned hsel = (unsigned)c0 >> 6;
    unsigned dd = (unsigned)c0 & 31;
    unsigned sub = (c0 & 32) ? 2u : 0u;
    char* q = xlp + (size_t)row * 256 + hsel * 128 + 4 * dd + sub;
#pragma unroll
    for (int j = 0; j < 4; ++j)
        *(unsigned short*)(q + 4 * j) = f2bf(a[j]);
}

// ---------------- Dual GEMM (layer 1, raw x input, K=3) ----------------

__global__ __launch_bounds__(256) void gemm_dual(const float* __restrict__ x,
                                                 const float* __restrict__ Wl,
                                                 const float* __restrict__ Wr,
                                                 char* __restrict__ xlp,
                                                 float* __restrict__ xr,
                                                 int n, int K) {
    __shared__ float xs[32][72];
    __shared__ float ws[32][260];
    int tid = threadIdx.x;
    int row0 = blockIdx.x * 64;
    int row_t = (tid >> 5) * 8;
    int c0 = (tid & 31) * 4;

    float acc0[8][4];
    float acc1[8][4];
#pragma unroll
    for (int i = 0; i < 8; ++i)
#pragma unroll
        for (int j = 0; j < 4; ++j) { acc0[i][j] = 0.f; acc1[i][j] = 0.f; }

    for (int k0 = 0; k0 < K; k0 += 32) {
        int kc = min(32, K - k0);
        for (int i = tid; i < 64 * kc; i += 256) {
            int r = i / kc;
            int k = i - r * kc;
            int row = row0 + r;
            xs[k][r] = (row < n) ? x[(size_t)row * K + k0 + k] : 0.f;
        }
        for (int i = tid; i < kc * 64; i += 256) {
            int k = i >> 6;
            int cq = i & 63;
            const float* srcp = (cq < 32) ? &Wl[(size_t)(k0 + k) * 128 + cq * 4]
                                          : &Wr[(size_t)(k0 + k) * 128 + (cq - 32) * 4];
            float4 v = *(const float4*)srcp;
            *(float4*)&ws[k][cq * 4] = v;
        }
        __syncthreads();
        for (int k = 0; k < kc; ++k) {
            float4 a0 = *(float4*)&xs[k][row_t];
            float4 a1 = *(float4*)&xs[k][row_t + 4];
            float4 b0 = *(float4*)&ws[k][c0];
            float4 b1 = *(float4*)&ws[k][c0 + 128];
            float av[8] = {a0.x, a0.y, a0.z, a0.w, a1.x, a1.y, a1.z, a1.w};
            float bl[4] = {b0.x, b0.y, b0.z, b0.w};
            float br[4] = {b1.x, b1.y, b1.z, b1.w};
#pragma unroll
            for (int i = 0; i < 8; ++i)
#pragma unroll
                for (int j = 0; j < 4; ++j) {
                    acc0[i][j] += av[i] * bl[j];
                    acc1[i][j] += av[i] * br[j];
                }
        }
        __syncthreads();
    }
#pragma unroll
    for (int i = 0; i < 8; ++i) {
        int row = row0 + row_t + i;
        if (row < n) {
            store_xlp(xlp, row, c0, acc0[i]);
            float4 o1; o1.x = acc1[i][0]; o1.y = acc1[i][1]; o1.z = acc1[i][2]; o1.w = acc1[i][3];
            *(float4*)&xr[(size_t)row * HC + c0] = o1;
        }
    }
}

// ---------------- Dual GEMM with fused graph-norm + ReLU (K=64) ----------------

__global__ __launch_bounds__(256) void gemm_fused(const float* __restrict__ h,
                                                  const float* __restrict__ cf,
                                                  const float* __restrict__ Wl,
                                                  const float* __restrict__ Wr,
                                                  char* __restrict__ xlp,
                                                  float* __restrict__ xr,
                                                  int n) {
    __shared__ float xs[64][76];
    __shared__ float ws[32][260];
    int tid = threadIdx.x;
    int row0 = blockIdx.x * 64;
    int row_t = (tid >> 5) * 8;
    int c0 = (tid & 31) * 4;

    {
        int r = tid >> 2;
        int b = tid & 3;
        int row = row0 + r;
#pragma unroll
        for (int i = 0; i < 4; ++i) {
            int c = 4 * b + 16 * i;
            float4 v;
            if (row < n) v = *(const float4*)&h[(size_t)row * 64 + c];
            else { v.x = v.y = v.z = v.w = 0.f; }
            float4 cw = *(const float4*)&cf[c];
            float4 cb = *(const float4*)&cf[64 + c];
            xs[c + 0][r] = fmaxf(fmaf(cw.x, v.x, cb.x), 0.f);
            xs[c + 1][r] = fmaxf(fmaf(cw.y, v.y, cb.y), 0.f);
            xs[c + 2][r] = fmaxf(fmaf(cw.z, v.z, cb.z), 0.f);
            xs[c + 3][r] = fmaxf(fmaf(cw.w, v.w, cb.w), 0.f);
        }
    }

    float acc0[8][4];
    float acc1[8][4];
#pragma unroll
    for (int i = 0; i < 8; ++i)
#pragma unroll
        for (int j = 0; j < 4; ++j) { acc0[i][j] = 0.f; acc1[i][j] = 0.f; }

    for (int k0 = 0; k0 < 64; k0 += 32) {
        if (k0) __syncthreads();
        for (int i = tid; i < 32 * 64; i += 256) {
            int k = i >> 6;
            int cq = i & 63;
            const float* srcp = (cq < 32) ? &Wl[(size_t)(k0 + k) * 128 + cq * 4]
                                          : &Wr[(size_t)(k0 + k) * 128 + (cq - 32) * 4];
            float4 v = *(const float4*)srcp;
            *(float4*)&ws[k][cq * 4] = v;
        }
        __syncthreads();
        for (int k = 0; k < 32; ++k) {
            float4 a0 = *(float4*)&xs[k0 + k][row_t];
            float4 a1 = *(float4*)&xs[k0 + k][row_t + 4];
            float4 b0 = *(float4*)&ws[k][c0];
            float4 b1 = *(float4*)&ws[k][c0 + 128];
            float av[8] = {a0.x, a0.y, a0.z, a0.w, a1.x, a1.y, a1.z, a1.w};
            float bl[4] = {b0.x, b0.y, b0.z, b0.w};
            float br[4] = {b1.x, b1.y, b1.z, b1.w};
#pragma unroll
            for (int i = 0; i < 8; ++i)
#pragma unroll
                for (int j = 0; j < 4; ++j) {
                    acc0[i][j] += av[i] * bl[j];
                    acc1[i][j] += av[i] * br[j];
                }
        }
    }
#pragma unroll
    for (int i = 0; i < 8; ++i) {
        int row = row0 + row_t + i;
        if (row < n) {
            store_xlp(xlp, row, c0, acc0[i]);
            float4 o1; o1.x = acc1[i][0]; o1.y = acc1[i][1]; o1.z = acc1[i][2]; o1.w = acc1[i][3];
            *(float4*)&xr[(size_t)row * HC + c0] = o1;
        }
    }
}

// ---------------- Attention (packed bf16 gathers: one uint per lane per edge) ----------------
// One wave per dst node. Lanes 0-31: head0 (dims laneh, laneh+32), lanes 32-63: head1.

__global__ __launch_bounds__(256) void attn_k(const char* __restrict__ xlp,
                                              const float* __restrict__ xr,
                                              const float* __restrict__ att,
                                              const float* __restrict__ bias,
                                              const int* __restrict__ row_ptr,
                                              const int* __restrict__ coloff,
                                              float* __restrict__ hout) {
    int lane = threadIdx.x & 63;
    int node = blockIdx.x * 4 + (threadIdx.x >> 6);
    if (node >= NN) return;
    int laneh = lane & 31;
    int lanebase = ((lane >> 5) << 8) | (laneh << 2);  // byte offset into 512B fp32 xr row
    bool b16 = (lane & 16) == 0;
    unsigned lp4 = (unsigned)lane * 4;                 // byte offset into 256B packed row

    const char* xrc = (const char*)xr;
    unsigned nodeoff = (unsigned)node << 9;

    float xrv1 = *(const float*)(xrc + nodeoff + lanebase);
    float xrv2 = *(const float*)(xrc + nodeoff + lanebase + 128);
    float a1 = att[lanebase >> 2];
    float a2 = att[(lanebase >> 2) + 32];
    float c11 = 0.6f * a1, c21 = 0.4f * a1;
    float c12 = 0.6f * a2, c22 = 0.4f * a2;

    float z = 0.f, o1 = 0.f, o2 = 0.f;

    int beg = row_ptr[node];
    int end = row_ptr[node + 1];
    int idx = beg;
    for (; idx + 8 <= end; idx += 8) {
        int offs[8];
#pragma unroll
        for (int j = 0; j < 8; ++j) offs[j] = coloff[idx + j];
        unsigned pk[8];
#pragma unroll
        for (int j = 0; j < 8; ++j)
            pk[j] = *(const unsigned*)(xlp + (unsigned)offs[j] + lp4);
        float l1[8], l2[8], u[8];
#pragma unroll
        for (int j = 0; j < 8; ++j) {
            l1[j] = __uint_as_float(pk[j] << 16);
            l2[j] = __uint_as_float(pk[j] & 0xffff0000u);
        }
#pragma unroll
        for (int j = 0; j < 8; ++j) {
            float t1 = l1[j] + xrv1;
            float t2 = l2[j] + xrv2;
            float v = fmaf(c11, t1, c21 * fabsf(t1));
            v = fmaf(c12, t2, v);
            u[j] = fmaf(c22, fabsf(t2), v);
        }
#pragma unroll
        for (int j = 0; j < 8; ++j) u[j] += __shfl_xor(u[j], 16, 64);
        float w0 = b16 ? u[0] : u[1];
        float w1 = b16 ? u[2] : u[3];
        float w2 = b16 ? u[4] : u[5];
        float w3 = b16 ? u[6] : u[7];
#pragma unroll
        for (int off = 8; off > 0; off >>= 1) {
            w0 += __shfl_xor(w0, off, 64);
            w1 += __shfl_xor(w1, off, 64);
            w2 += __shfl_xor(w2, off, 64);
            w3 += __shfl_xor(w3, off, 64);
        }
        float s0 = __shfl_xor(w0, 16, 64);
        float s1 = __shfl_xor(w1, 16, 64);
        float s2 = __shfl_xor(w2, 16, 64);
        float s3 = __shfl_xor(w3, 16, 64);
        float p0 = __expf(b16 ? w0 : s0);
        float p1 = __expf(b16 ? s0 : w0);
        float p2 = __expf(b16 ? w1 : s1);
        float p3 = __expf(b16 ? s1 : w1);
        float p4 = __expf(b16 ? w2 : s2);
        float p5 = __expf(b16 ? s2 : w2);
        float p6 = __expf(b16 ? w3 : s3);
        float p7 = __expf(b16 ? s3 : w3);
        z += ((p0 + p1) + (p2 + p3)) + ((p4 + p5) + (p6 + p7));
        o1 = fmaf(p0, l1[0], o1); o2 = fmaf(p0, l2[0], o2);
        o1 = fmaf(p1, l1[1], o1); o2 = fmaf(p1, l2[1], o2);
        o1 = fmaf(p2, l1[2], o1); o2 = fmaf(p2, l2[2], o2);
        o1 = fmaf(p3, l1[3], o1); o2 = fmaf(p3, l2[3], o2);
        o1 = fmaf(p4, l1[4], o1); o2 = fmaf(p4, l2[4], o2);
        o1 = fmaf(p5, l1[5], o1); o2 = fmaf(p5, l2[5], o2);
        o1 = fmaf(p6, l1[6], o1); o2 = fmaf(p6, l2[6], o2);
        o1 = fmaf(p7, l1[7], o1); o2 = fmaf(p7, l2[7], o2);
    }
    for (; idx < end; ++idx) {
        unsigned pk = *(const unsigned*)(xlp + (unsigned)coloff[idx] + lp4);
        float l1 = __uint_as_float(pk << 16);
        float l2 = __uint_as_float(pk & 0xffff0000u);
        float t1 = l1 + xrv1;
        float t2 = l2 + xrv2;
        float v = fmaf(c11, t1, c21 * fabsf(t1));
        v = fmaf(c12, t2, v);
        float u = fmaf(c22, fabsf(t2), v);
#pragma unroll
        for (int off = 16; off > 0; off >>= 1) u += __shfl_xor(u, off, 64);
        float pj = __expf(u);
        z += pj;
        o1 = fmaf(pj, l1, o1);
        o2 = fmaf(pj, l2, o2);
    }
    float zi = 1.0f / z;
    float t1 = o1 * zi;
    float t2 = o2 * zi;
    float u1 = __shfl_xor(t1, 32, 64);
    float u2 = __shfl_xor(t2, 32, 64);
    if (lane < 32) {
        float r1 = fmaf(0.5f, t1 + u1, bias[laneh]);
        float r2 = fmaf(0.5f, t2 + u2, bias[laneh + 32]);
        float* q = hout + (size_t)node * 64 + laneh;
        q[0] = r1;
        q[32] = r2;
    }
}

// ---------------- GraphNorm stats + coefficient (fused via last-block ticket) ----------------

__global__ __launch_bounds__(256) void colstats_k(const float* __restrict__ h,
                                                  const float* __restrict__ gw,
                                                  const float* __restrict__ gb,
                                                  const float* __restrict__ gm,
                                                  float* __restrict__ stats,
                                                  int* __restrict__ ticket,
                                                  float* __restrict__ cf) {
    int c = threadIdx.x & 63;
    int rg = threadIdx.x >> 6;
    float s = 0.f, s2 = 0.f;
    for (int r = blockIdx.x * 4 + rg; r < NN; r += gridDim.x * 4) {
        float v = h[(size_t)r * 64 + c];
        s += v;
        s2 += v * v;
    }
    __shared__ float b1[4][64];
    __shared__ float b2[4][64];
    b1[rg][c] = s;
    b2[rg][c] = s2;
    __syncthreads();
    if (threadIdx.x < 64) {
        s = b1[0][c] + b1[1][c] + b1[2][c] + b1[3][c];
        s2 = b2[0][c] + b2[1][c] + b2[2][c] + b2[3][c];
        atomicAdd(&stats[c], s);
        atomicAdd(&stats[64 + c], s2);
    }
    __shared__ int lastFlag;
    __threadfence();
    if (threadIdx.x == 0) {
        int t = __hip_atomic_fetch_add(ticket, 1, __ATOMIC_ACQ_REL, __HIP_MEMORY_SCOPE_AGENT);
        lastFlag = (t == (int)gridDim.x - 1);
    }
    __syncthreads();
    if (lastFlag && threadIdx.x < 64) {
        float sum = __hip_atomic_load(&stats[c], __ATOMIC_RELAXED, __HIP_MEMORY_SCOPE_AGENT);
        float sum2 = __hip_atomic_load(&stats[64 + c], __ATOMIC_RELAXED, __HIP_MEMORY_SCOPE_AGENT);
        float inv_n = 1.f / (float)NN;
        float mu = sum * inv_n;
        float ex2 = sum2 * inv_n;
        float g = gm[c];
        float var = ex2 - 2.f * g * mu * mu + g * g * mu * mu;
        float rs = rsqrtf(var + EPSV);
        cf[c] = gw[c] * rs;
        cf[64 + c] = gb[c] - gw[c] * rs * g * mu;
    }
}

__global__ __launch_bounds__(256) void apply_k(const float* __restrict__ h,
                                               const float* __restrict__ cf,
                                               float* __restrict__ y) {
    int i = blockIdx.x * 256 + threadIdx.x;
    if (i >= NN * 64) return;
    int c = i & 63;
    float v = fmaf(cf[c], h[i], cf[64 + c]);
    y[i] = fmaxf(v, 0.f);
}

// ---------------- launch ----------------

extern "C" void kernel_launch(void* const* d_in, const int* in_sizes, int n_in,
                              void* d_out, int out_size, void* d_ws, size_t ws_size,
                              hipStream_t stream) {
    const float* x0 = (const float*)d_in[0];
    const int* ei = (const int*)d_in[1];
    const int* srcp = ei;
    const int* dstp = ei + NE;

    const float* Wl[3], *Wr[3], *att[3], *bv[3], *gw[3], *gb[3], *gm[3];
    for (int l = 0; l < 3; ++l) {
        int base = 2 + 7 * l;
        Wl[l] = (const float*)d_in[base + 0];
        Wr[l] = (const float*)d_in[base + 1];
        att[l] = (const float*)d_in[base + 2];
        bv[l] = (const float*)d_in[base + 3];
        gw[l] = (const float*)d_in[base + 4];
        gb[l] = (const float*)d_in[base + 5];
        gm[l] = (const float*)d_in[base + 6];
    }

    char* p = (char*)d_ws;
    auto take = [&](size_t bytes) -> void* {
        void* r = (void*)p;
        p += (bytes + 255) & ~(size_t)255;
        return r;
    };
    char* xlp = (char*)take((size_t)NN * 256);         // packed bf16 attention operand
    float* xr = (float*)take((size_t)NN * 128 * 4);
    float* hb = (float*)take((size_t)NN * 64 * 4);
    size_t zero_bytes = 3 * 128 * 4 + 3 * 4 + (size_t)NN * 4;
    char* zr = (char*)take(zero_bytes);
    float* stats = (float*)zr;
    int* tickets = (int*)(zr + 3 * 128 * 4);
    int* cnt = (int*)(zr + 3 * 128 * 4 + 3 * 4);
    int* row_ptr = (int*)take((size_t)(NN + 1) * 4);
    int* rank = (int*)take((size_t)TE * 4);
    int* col = (int*)take((size_t)TE * 4);
    int* aux = (int*)take(64 * 4);
    float* cfb = (float*)take(3 * 128 * 4);

    hipMemsetAsync(zr, 0, zero_bytes, stream);

    int nblk = (NN + 1023) / 1024;
    int egrid = (TE + 255) / 256;
    count_k<<<egrid, 256, 0, stream>>>(dstp, cnt, rank);
    scan1_k<<<nblk, 1024, 0, stream>>>(cnt, row_ptr, aux);
    scan3_k<<<nblk, 1024, 0, stream>>>(row_ptr, aux, nblk);
    scatter_k<<<egrid, 256, 0, stream>>>(srcp, dstp, row_ptr, rank, col);

    int ggrid = (NN + 63) / 64;
    int agrid = (NN + 3) / 4;
    for (int l = 0; l < 3; ++l) {
        float* cf = cfb + l * 128;
        if (l == 0)
            gemm_dual<<<ggrid, 256, 0, stream>>>(x0, Wl[0], Wr[0], xlp, xr, NN, 3);
        else
            gemm_fused<<<ggrid, 256, 0, stream>>>(hb, cfb + (l - 1) * 128, Wl[l], Wr[l], xlp, xr, NN);
        attn_k<<<agrid, 256, 0, stream>>>(xlp, xr, att[l], bv[l], row_ptr, col, hb);
        colstats_k<<<STATS_BLOCKS, 256, 0, stream>>>(hb, gw[l], gb[l], gm[l],
                                                     stats + l * 128, tickets + l, cf);
    }
    apply_k<<<(NN * 64 + 255) / 256, 256, 0, stream>>>(hb, cfb + 2 * 128, (float*)d_out);
}